// Round 1
// baseline (153.119 us; speedup 1.0000x reference)
//
#include <hip/hip_runtime.h>

#define GYD 1024
#define GXD 1024
#define NUM_BEV 8

// ---- wave-wide butterfly reductions (64 lanes) ----
__device__ __forceinline__ float wsum(float x) {
#pragma unroll
    for (int o = 1; o < 64; o <<= 1) x += __shfl_xor(x, o, 64);
    return x;
}
__device__ __forceinline__ float wmaxr(float x) {
#pragma unroll
    for (int o = 1; o < 64; o <<= 1) x = fmaxf(x, __shfl_xor(x, o, 64));
    return x;
}
__device__ __forceinline__ float wminr(float x) {
#pragma unroll
    for (int o = 1; o < 64; o <<= 1) x = fminf(x, __shfl_xor(x, o, 64));
    return x;
}

// One wave per pillar; 4 pillars per 256-thread block.
__global__ __launch_bounds__(256) void pillar_kernel(
    const float4* __restrict__ vf,       // N*32 points (x,y,z,intensity)
    const float* __restrict__ W,         // 10 x 64 row-major
    const float* __restrict__ gammap, const float* __restrict__ betap,
    const float* __restrict__ rmean, const float* __restrict__ rvar,
    const int* __restrict__ npts_arr,
    const int* __restrict__ coords,      // N x 4: (b, zc, y, x)
    float* __restrict__ pillar_out,      // N*64
    float* __restrict__ bev_vals,        // N*8
    int* __restrict__ winner,            // bs*GY*GX
    int N, int bs)
{
    __shared__ float4 pts[4][32];
    const int wid  = threadIdx.x >> 6;
    const int lane = threadIdx.x & 63;
    const int n    = blockIdx.x * 4 + wid;
    const bool valid = (n < N);
    const int nn = valid ? n : 0;

    const int npts = npts_arr[nn];
    const int cb   = coords[nn * 4 + 0];
    const int czi  = coords[nn * 4 + 1];
    const int cyi  = coords[nn * 4 + 2];
    const int cxi  = coords[nn * 4 + 3];
    // VX=VY=0.1, VZ=4.0; X_OFF=Y_OFF=0.05-51.2=-51.15; Z_OFF=2.0-3.0=-1.0
    const float cx = (float)cxi * 0.1f - 51.15f;
    const float cy = (float)cyi * 0.1f - 51.15f;
    const float cz = (float)czi * 4.0f - 1.0f;

    float4 v = make_float4(0.f, 0.f, 0.f, 0.f);
    bool pv = false;
    if (valid && lane < 32) {
        v = vf[(size_t)nn * 32 + lane];
        pv = (lane < npts);
        pts[wid][lane] = v;
    }
    const float m    = pv ? 1.f : 0.f;
    const float fn   = (float)npts;
    const float invn = 1.f / fn;

    // unmasked xyz sums (reference divides unmasked sum by npts)
    const float mx_ = wsum(v.x) * invn;
    const float my_ = wsum(v.y) * invn;
    const float mz_ = wsum(v.z) * invn;

    // masked sums
    const float msx = wsum(v.x * m);
    const float msy = wsum(v.y * m);
    const float msz = wsum(v.z * m);
    const float mI  = wsum(v.w * m);
    const float pmx = msx * invn, pmy = msy * invn, pmz = msz * invn;

    const float maxz = wmaxr(pv ? v.z : -1e6f);
    const float minz = wminr(pv ? v.z :  1e6f);

    const float dx = v.x - pmx, dy = v.y - pmy, dz = v.z - pmz;
    const float vvx = wsum(dx * dx * m) * invn;
    const float vvy = wsum(dy * dy * m) * invn;
    const float vvz = wsum(dz * dz * m) * invn;

    __syncthreads();

    // ---- per-channel phase: lane = output channel d ----
    const int d = lane;
    const float w0 = W[d],        w1 = W[64 + d],  w2 = W[128 + d], w3 = W[192 + d];
    const float w4 = W[256 + d],  w5 = W[320 + d], w6 = W[384 + d];
    const float w7 = W[448 + d],  w8 = W[512 + d], w9 = W[576 + d];
    const float g  = gammap[d], bt = betap[d], rm = rmean[d], rv = rvar[d];
    const float scale = g * rsqrtf(rv + 1e-3f);
    const float shift = bt - rm * scale;   // BN output of an all-zero (masked) row
    const float A = (w0 + w4 + w7) * scale;
    const float B = (w1 + w5 + w8) * scale;
    const float C = (w2 + w6 + w9) * scale;
    const float D = w3 * scale;
    const float E = -(mx_ * w4 + my_ * w5 + mz_ * w6 + cx * w7 + cy * w8 + cz * w9);
    const float base = E * scale + shift;

    float acc = -1e30f;
    for (int p = 0; p < npts; ++p) {   // wave-uniform trip count
        const float4 q = pts[wid][p];  // LDS broadcast, conflict-free
        const float t = fmaf(q.x, A, fmaf(q.y, B, fmaf(q.z, C, fmaf(q.w, D, base))));
        acc = fmaxf(acc, t);
    }
    if (npts < 32) acc = fmaxf(acc, shift);  // masked rows participate in the max
    acc = fmaxf(acc, 0.f);                   // ReLU commutes with max

    if (valid) {
        pillar_out[(size_t)n * 64 + lane] = acc;
        if (lane == 0) {
            const float b0 = fn * (1.f / 32.f);
            const float b1 = mI * invn;
            const float b2 = msz * invn;
            float4* bvp = (float4*)&bev_vals[(size_t)n * 8];
            bvp[0] = make_float4(b0, b1, b2, maxz);
            bvp[1] = make_float4(maxz - minz, vvx, vvy, vvz);
            int b = cb < 0 ? 0 : (cb > bs - 1 ? bs - 1 : cb);
            const int cell = (b * GYD + cyi) * GXD + cxi;
            atomicMax(&winner[cell], n + 1);  // last-write-wins = max pillar index
        }
    }
}

__global__ __launch_bounds__(256) void scatter_kernel(
    const int* __restrict__ coords,
    const float* __restrict__ bev_vals,
    const int* __restrict__ winner,
    float* __restrict__ vox_bev,   // bs*8*GY*GX
    int N, int bs)
{
    const int n = blockIdx.x * blockDim.x + threadIdx.x;
    if (n >= N) return;
    const int cb = coords[n * 4 + 0];
    const int y  = coords[n * 4 + 2];
    const int x  = coords[n * 4 + 3];
    const int b  = cb < 0 ? 0 : (cb > bs - 1 ? bs - 1 : cb);
    const int cell = (b * GYD + y) * GXD + x;
    if (winner[cell] == n + 1) {
#pragma unroll
        for (int k = 0; k < NUM_BEV; ++k)
            vox_bev[(((size_t)b * NUM_BEV + k) * GYD + y) * GXD + x] = bev_vals[(size_t)n * 8 + k];
    }
}

extern "C" void kernel_launch(void* const* d_in, const int* in_sizes, int n_in,
                              void* d_out, int out_size, void* d_ws, size_t ws_size,
                              hipStream_t stream) {
    const float4* vf    = (const float4*)d_in[0];
    const float* W      = (const float*)d_in[1];
    const float* gammap = (const float*)d_in[2];
    const float* betap  = (const float*)d_in[3];
    const float* rmean  = (const float*)d_in[4];
    const float* rvar   = (const float*)d_in[5];
    const int* npts     = (const int*)d_in[6];
    const int* coords   = (const int*)d_in[7];
    const int N  = in_sizes[6];
    const int bs = in_sizes[8];

    float* pillar_out = (float*)d_out;                        // N*64
    float* vox_bev    = (float*)d_out + (size_t)N * 64;       // bs*8*GY*GX

    int* winner     = (int*)d_ws;                             // bs*GY*GX ints
    float* bev_vals = (float*)((char*)d_ws + (size_t)bs * GYD * GXD * sizeof(int)); // N*8

    hipMemsetAsync(winner, 0, (size_t)bs * GYD * GXD * sizeof(int), stream);
    hipMemsetAsync(vox_bev, 0, (size_t)bs * NUM_BEV * GYD * GXD * sizeof(float), stream);

    const int blocksA = (N + 3) / 4;   // 4 pillars (waves) per block
    pillar_kernel<<<blocksA, 256, 0, stream>>>(vf, W, gammap, betap, rmean, rvar,
                                               npts, coords, pillar_out, bev_vals,
                                               winner, N, bs);
    const int blocksB = (N + 255) / 256;
    scatter_kernel<<<blocksB, 256, 0, stream>>>(coords, bev_vals, winner, vox_bev, N, bs);
}